// Round 1
// baseline (544.502 us; speedup 1.0000x reference)
//
#include <hip/hip_runtime.h>

// GHMC loss, fused single-pass:
//   loss = sum_b L_b / (cnt_b * n_nonempty),  b over bins with cnt_b > 0
// where L_b = sum over elements in bin b of BCE-with-logits loss
//   l(x,t) = max(x,0) - x*t + log(1 + exp(-|x|))
// and bin b holds g = |x-t| with edges[b] <= g < edges[b+1],
// edges = {0, .1, ..., .9, 1.0+1e-6} (float32, matching jnp.arange/10).
//
// Cumulative-GE histogram: slot b accumulates {count, loss-sum} of all
// elements with g >= edges[b]; per-bin values recovered by differencing
// in the finalize kernel. Slot 0 (g >= 0) is unconditional.

#define NSLOTS 11  // 10 bins + out-of-range cumulative slot

__device__ __forceinline__ void proc(float x, float t,
                                     float (&sum)[NSLOTS],
                                     unsigned (&cnt)[NSLOTS]) {
    // float32 edges exactly as in the reference (i/10 correctly rounded)
    const float edges[NSLOTS] = {0.0f, 0.1f, 0.2f, 0.3f, 0.4f, 0.5f,
                                 0.6f, 0.7f, 0.8f, 0.9f, 1.0f + 1e-6f};
    float g = fabsf(x - t);
    // positive BCE-with-logits loss (stable form); hw exp/log are ~2ulp,
    // negligible vs 1.2e-2 scalar threshold
    float l = fmaxf(x, 0.0f) - x * t + __logf(1.0f + __expf(-fabsf(x)));
    sum[0] += l;
    cnt[0] += 1u;
#pragma unroll
    for (int b = 1; b < NSLOTS; ++b) {
        bool m = (g >= edges[b]);
        cnt[b] += m ? 1u : 0u;
        sum[b] += m ? l : 0.0f;
    }
}

__global__ __launch_bounds__(256) void ghmc_partial(
    const float4* __restrict__ p4, const float4* __restrict__ t4, int n4,
    const float* __restrict__ p1, const float* __restrict__ t1, long long ntot,
    double* __restrict__ g_sum, unsigned int* __restrict__ g_cnt) {
    float sum[NSLOTS];
    unsigned cnt[NSLOTS];
#pragma unroll
    for (int b = 0; b < NSLOTS; ++b) { sum[b] = 0.0f; cnt[b] = 0u; }

    int stride = gridDim.x * blockDim.x;
    for (int i = blockIdx.x * blockDim.x + threadIdx.x; i < n4; i += stride) {
        float4 p = p4[i];
        float4 t = t4[i];
        proc(p.x, t.x, sum, cnt);
        proc(p.y, t.y, sum, cnt);
        proc(p.z, t.z, sum, cnt);
        proc(p.w, t.w, sum, cnt);
    }
    // scalar tail (ntot not divisible by 4) — handled by one thread
    if (blockIdx.x == 0 && threadIdx.x == 0) {
        for (long long j = (long long)n4 * 4; j < ntot; ++j)
            proc(p1[j], t1[j], sum, cnt);
    }

    // wave (64-lane) tree reduction of all 22 accumulators
#pragma unroll
    for (int off = 32; off > 0; off >>= 1) {
#pragma unroll
        for (int b = 0; b < NSLOTS; ++b) {
            sum[b] += __shfl_down(sum[b], off, 64);
            cnt[b] += __shfl_down(cnt[b], off, 64);
        }
    }

    __shared__ float s_sum[4][NSLOTS];
    __shared__ unsigned s_cnt[4][NSLOTS];
    int wave = threadIdx.x >> 6;
    int lane = threadIdx.x & 63;
    if (lane == 0) {
#pragma unroll
        for (int b = 0; b < NSLOTS; ++b) {
            s_sum[wave][b] = sum[b];
            s_cnt[wave][b] = cnt[b];
        }
    }
    __syncthreads();
    if (threadIdx.x < NSLOTS) {
        int b = threadIdx.x;
        float fs = s_sum[0][b] + s_sum[1][b] + s_sum[2][b] + s_sum[3][b];
        unsigned c = s_cnt[0][b] + s_cnt[1][b] + s_cnt[2][b] + s_cnt[3][b];
        atomicAdd(&g_sum[b], (double)fs);  // global f64 atomic: tiny count (2048/bin)
        atomicAdd(&g_cnt[b], c);
    }
}

__global__ void ghmc_final(const double* __restrict__ g_sum,
                           const unsigned int* __restrict__ g_cnt,
                           float* __restrict__ out) {
    if (blockIdx.x == 0 && threadIdx.x == 0) {
        double loss = 0.0;
        int n = 0;
        double per_bin[10];
        double per_cnt[10];
#pragma unroll
        for (int b = 0; b < 10; ++b) {
            unsigned c = g_cnt[b] - g_cnt[b + 1];
            per_cnt[b] = (double)c;
            per_bin[b] = g_sum[b] - g_sum[b + 1];
            n += (c > 0u) ? 1 : 0;
        }
        double nn = (n > 0) ? (double)n : 1.0;
#pragma unroll
        for (int b = 0; b < 10; ++b) {
            if (per_cnt[b] > 0.0) loss += per_bin[b] / per_cnt[b];
        }
        loss /= nn;
        out[0] = (float)loss;
    }
}

extern "C" void kernel_launch(void* const* d_in, const int* in_sizes, int n_in,
                              void* d_out, int out_size, void* d_ws, size_t ws_size,
                              hipStream_t stream) {
    const float* pred = (const float*)d_in[0];
    const float* tgt  = (const float*)d_in[1];
    long long ntot = (long long)in_sizes[0];
    int n4 = (int)(ntot / 4);

    double* g_sum = (double*)d_ws;                                   // 11 doubles
    unsigned int* g_cnt = (unsigned int*)((char*)d_ws + NSLOTS * sizeof(double));

    // d_ws is poisoned to 0xAA before every timed launch — zero our accumulators
    hipMemsetAsync(d_ws, 0, NSLOTS * sizeof(double) + NSLOTS * sizeof(unsigned int),
                   stream);

    const int threads = 256;
    const int blocks = 2048;  // 8 blocks/CU, grid-stride: 32 float4 iters/thread
    hipLaunchKernelGGL(ghmc_partial, dim3(blocks), dim3(threads), 0, stream,
                       (const float4*)pred, (const float4*)tgt, n4,
                       pred, tgt, ntot, g_sum, g_cnt);
    hipLaunchKernelGGL(ghmc_final, dim3(1), dim3(64), 0, stream,
                       g_sum, g_cnt, (float*)d_out);
}